// Round 17
// baseline (508.353 us; speedup 1.0000x reference)
//
#include <hip/hip_runtime.h>
#include <hip/hip_cooperative_groups.h>
#include <stdint.h>

namespace cg = cooperative_groups;

#define C 128
#define ALPHA_F 0.1f
#define ONE_MINUS_ALPHA 0.9f
// beta = log(THETA/LAYER + 1) = log(1.25)
#define BETA_F 0.22314355131420976f
#define ONE_MINUS_BETA 0.7768564486857902f

typedef __attribute__((ext_vector_type(8))) short bf16x8;
typedef __attribute__((ext_vector_type(4))) float f32x4;

__device__ inline float bf2f(unsigned short u) {
    union { unsigned int i; float f; } c;
    c.i = ((unsigned int)u) << 16;
    return c.f;
}
__device__ inline unsigned short f2bf(float f) {
    union { float f; unsigned int i; } c;
    c.f = f;
    unsigned int r = (c.i + 0x7FFFu + ((c.i >> 16) & 1u)) >> 16;  // RNE
    return (unsigned short)r;
}

// ---------------- cooperative preprocessing mega-kernel ----------------
// Phases (grid.sync between): 0) zero cnt + build Vb   1) hist + rank
// 2a) per-256-chunk sums -> part   2b) exclusive scan -> meta/row_ptr/dinv
// 3) place edges (no atomics) + y = bf16(x*dinv).
// Replaces 5 dispatches (init/hist/scan_a/scan_bc/pl_ybf) -> 1.
__global__ __launch_bounds__(256)
void k_pre(const float* __restrict__ W, unsigned short* __restrict__ Vb,
           int* __restrict__ cnt, int* __restrict__ rank,
           const int* __restrict__ src, const int* __restrict__ dst,
           int* __restrict__ row_ptr, int4* __restrict__ meta,
           float* __restrict__ dinv, int* __restrict__ part,
           int* __restrict__ sorted_src,
           const float* __restrict__ x, unsigned short* __restrict__ y,
           int n, int e, int nb) {
    cg::grid_group grid = cg::this_grid();
    __shared__ int sa[256];
    __shared__ int sb[256];

    int tid     = threadIdx.x;
    int gsz     = gridDim.x;
    int gtid    = blockIdx.x * 256 + tid;
    int gstride = gsz * 256;

    // phase 0: zero cnt + V = (1-beta)*I + beta*W^T (bf16)
    for (int i = gtid; i < n; i += gstride) cnt[i] = 0;
    for (int i = gtid; i < C * C; i += gstride) {
        int j = i >> 7;
        int c = i & 127;
        Vb[i] = f2bf(BETA_F * W[i] + ((j == c) ? ONE_MINUS_BETA : 0.f));
    }
    grid.sync();

    // phase 1: hist; the atomic's return value IS the placement rank
    for (int i = gtid; i < e; i += gstride) rank[i] = atomicAdd(&cnt[dst[i]], 1);
    grid.sync();

    // phase 2a: 256-chunk sums -> part
    for (int vb = blockIdx.x; vb < nb; vb += gsz) {
        int i = vb * 256 + tid;
        sa[tid] = (i < n) ? cnt[i] : 0;
        __syncthreads();
        for (int off = 128; off > 0; off >>= 1) {
            if (tid < off) sa[tid] += sa[tid + off];
            __syncthreads();
        }
        if (tid == 0) part[vb] = sa[0];
        __syncthreads();
    }
    grid.sync();

    // phase 2b: per-chunk exclusive scan + meta/row_ptr/dinv
    for (int vb = blockIdx.x; vb < nb; vb += gsz) {
        int local = 0;
        for (int k = tid; k < vb; k += 256) local += part[k];
        sa[tid] = local;
        __syncthreads();
        for (int off = 128; off > 0; off >>= 1) {
            if (tid < off) sa[tid] += sa[tid + off];
            __syncthreads();
        }
        int blockoff = sa[0];
        __syncthreads();

        int i = vb * 256 + tid;
        int v = (i < n) ? cnt[i] : 0;
        sa[tid] = v;
        __syncthreads();
        int* cur = sa;
        int* nxt = sb;
        for (int off = 1; off < 256; off <<= 1) {
            nxt[tid] = cur[tid] + ((tid >= off) ? cur[tid - off] : 0);
            __syncthreads();
            int* tmp = cur; cur = nxt; nxt = tmp;
        }
        if (i < n) {
            int rp = blockoff + cur[tid] - v;
            float dv = rsqrtf((float)(v + 1));     // deg includes self-loop
            meta[i]    = make_int4(rp, v, __float_as_int(dv), 0);
            row_ptr[i] = rp;
            dinv[i]    = dv;
        }
        __syncthreads();
    }
    grid.sync();

    // phase 3: place (no atomics) + y build
    for (int i = gtid; i < e; i += gstride) {
        int d = dst[i];
        sorted_src[row_ptr[d] + rank[i]] = src[i];
    }
    int total = n * 32;
    for (int t = gtid; t < total; t += gstride) {
        int i = t >> 5;
        float dv = dinv[i];
        float4 v = ((const float4*)x)[t];
        ushort4 o;
        o.x = f2bf(v.x * dv);
        o.y = f2bf(v.y * dv);
        o.z = f2bf(v.z * dv);
        o.w = f2bf(v.w * dv);
        ((ushort4*)y)[t] = o;
    }
}

// per-node accumulate: 8 weight-clamped up-front loads + 4-wide batches to 32
// + uniform tail. eidx holds this half-wave's preloaded edge list.
__device__ __forceinline__ float4 acc_node(const ushort4* __restrict__ y4,
                                           const int* __restrict__ ss,
                                           int node, int start, int len,
                                           int eidx, int l32, int base) {
    int m = (len < 32) ? len : 32;
    bool b1 = 1 < m, b2 = 2 < m, b3 = 3 < m;
    bool b4 = 4 < m, b5 = 5 < m, b6 = 6 < m, b7 = 7 < m;
    int s0 = __shfl(eidx, base + 0, 64);
    int s1 = __shfl(eidx, base + (b1 ? 1 : 0), 64);
    int s2 = __shfl(eidx, base + (b2 ? 2 : 0), 64);
    int s3 = __shfl(eidx, base + (b3 ? 3 : 0), 64);
    int s4 = __shfl(eidx, base + (b4 ? 4 : 0), 64);
    int s5 = __shfl(eidx, base + (b5 ? 5 : 0), 64);
    int s6 = __shfl(eidx, base + (b6 ? 6 : 0), 64);
    int s7 = __shfl(eidx, base + (b7 ? 7 : 0), 64);
    ushort4 v0 = y4[(size_t)s0 * 32 + l32];
    ushort4 v1 = y4[(size_t)s1 * 32 + l32];
    ushort4 v2 = y4[(size_t)s2 * 32 + l32];
    ushort4 v3 = y4[(size_t)s3 * 32 + l32];
    ushort4 v4 = y4[(size_t)s4 * 32 + l32];
    ushort4 v5 = y4[(size_t)s5 * 32 + l32];
    ushort4 v6 = y4[(size_t)s6 * 32 + l32];
    ushort4 v7 = y4[(size_t)s7 * 32 + l32];
    ushort4 vs = y4[(size_t)node * 32 + l32];   // self-loop row

    float w0 = (0 < m) ? 1.f : 0.f, w1 = b1 ? 1.f : 0.f, w2 = b2 ? 1.f : 0.f, w3 = b3 ? 1.f : 0.f;
    float w4 = b4 ? 1.f : 0.f, w5 = b5 ? 1.f : 0.f, w6 = b6 ? 1.f : 0.f, w7 = b7 ? 1.f : 0.f;

    float4 acc;
    acc.x = bf2f(vs.x) + w0 * bf2f(v0.x) + w1 * bf2f(v1.x) + w2 * bf2f(v2.x) + w3 * bf2f(v3.x)
                       + w4 * bf2f(v4.x) + w5 * bf2f(v5.x) + w6 * bf2f(v6.x) + w7 * bf2f(v7.x);
    acc.y = bf2f(vs.y) + w0 * bf2f(v0.y) + w1 * bf2f(v1.y) + w2 * bf2f(v2.y) + w3 * bf2f(v3.y)
                       + w4 * bf2f(v4.y) + w5 * bf2f(v5.y) + w6 * bf2f(v6.y) + w7 * bf2f(v7.y);
    acc.z = bf2f(vs.z) + w0 * bf2f(v0.z) + w1 * bf2f(v1.z) + w2 * bf2f(v2.z) + w3 * bf2f(v3.z)
                       + w4 * bf2f(v4.z) + w5 * bf2f(v5.z) + w6 * bf2f(v6.z) + w7 * bf2f(v7.z);
    acc.w = bf2f(vs.w) + w0 * bf2f(v0.w) + w1 * bf2f(v1.w) + w2 * bf2f(v2.w) + w3 * bf2f(v3.w)
                       + w4 * bf2f(v4.w) + w5 * bf2f(v5.w) + w6 * bf2f(v6.w) + w7 * bf2f(v7.w);

    for (int j = 8; j < m; j += 4) {
        bool c1 = (j + 1) < m, c2 = (j + 2) < m, c3 = (j + 3) < m;
        int t0 = __shfl(eidx, base + j, 64);
        int t1 = __shfl(eidx, base + (c1 ? j + 1 : j), 64);
        int t2 = __shfl(eidx, base + (c2 ? j + 2 : j), 64);
        int t3 = __shfl(eidx, base + (c3 ? j + 3 : j), 64);
        ushort4 u0 = y4[(size_t)t0 * 32 + l32];
        ushort4 u1 = y4[(size_t)t1 * 32 + l32];
        ushort4 u2 = y4[(size_t)t2 * 32 + l32];
        ushort4 u3 = y4[(size_t)t3 * 32 + l32];
        float q1 = c1 ? 1.f : 0.f, q2 = c2 ? 1.f : 0.f, q3 = c3 ? 1.f : 0.f;
        acc.x += bf2f(u0.x) + q1 * bf2f(u1.x) + q2 * bf2f(u2.x) + q3 * bf2f(u3.x);
        acc.y += bf2f(u0.y) + q1 * bf2f(u1.y) + q2 * bf2f(u2.y) + q3 * bf2f(u3.y);
        acc.z += bf2f(u0.z) + q1 * bf2f(u1.z) + q2 * bf2f(u2.z) + q3 * bf2f(u3.z);
        acc.w += bf2f(u0.w) + q1 * bf2f(u1.w) + q2 * bf2f(u2.w) + q3 * bf2f(u3.w);
    }

    for (int j = 32; j < len; ++j) {     // rare: degree > 32
        int t0 = ss[start + j];
        ushort4 u0 = y4[(size_t)t0 * 32 + l32];
        acc.x += bf2f(u0.x);
        acc.y += bf2f(u0.y);
        acc.z += bf2f(u0.z);
        acc.w += bf2f(u0.w);
    }
    return acc;
}

// ---------------- gather + alpha-blend -> s (bf16 ws or fp32 d_out) --------
// 2 nodes per HALF-WAVE, front-loads paired.
__global__ __launch_bounds__(256)
void k_gather(const unsigned short* __restrict__ y, const float* __restrict__ x0,
              const int* __restrict__ sorted_src, const int4* __restrict__ meta,
              float* __restrict__ soutf, unsigned short* __restrict__ soutb,
              int mode, int n) {
    int tid  = threadIdx.x;
    int l32  = tid & 31;
    int base = tid & 32;
    int hw   = tid >> 5;                  // 0..7 half-wave in block
    int node0 = blockIdx.x * 16 + hw * 2;
    if (node0 >= n) return;
    int node1 = node0 + 1;
    bool ok1 = node1 < n;
    int vn1 = ok1 ? node1 : node0;

    const ushort4* y4 = (const ushort4*)y;
    const f32x4* x04 = (const f32x4*)x0;

    int4 md0 = meta[node0];
    int4 md1 = meta[vn1];
    int m0 = (md0.y < 32) ? md0.y : 32;
    int m1 = (md1.y < 32) ? md1.y : 32;
    int e0 = (l32 < m0) ? sorted_src[md0.x + l32] : node0;
    int e1 = (l32 < m1) ? sorted_src[md1.x + l32] : vn1;
    f32x4 xv0 = __builtin_nontemporal_load(x04 + (size_t)node0 * 32 + l32);
    f32x4 xv1 = __builtin_nontemporal_load(x04 + (size_t)vn1 * 32 + l32);

    float4 a0 = acc_node(y4, sorted_src, node0, md0.x, md0.y, e0, l32, base);
    float4 a1 = acc_node(y4, sorted_src, vn1,   md1.x, md1.y, e1, l32, base);

    float dv0 = __int_as_float(md0.z);
    float dv1 = __int_as_float(md1.z);

    float4 s0, s1;
    s0.x = ONE_MINUS_ALPHA * (dv0 * a0.x) + ALPHA_F * xv0.x;
    s0.y = ONE_MINUS_ALPHA * (dv0 * a0.y) + ALPHA_F * xv0.y;
    s0.z = ONE_MINUS_ALPHA * (dv0 * a0.z) + ALPHA_F * xv0.z;
    s0.w = ONE_MINUS_ALPHA * (dv0 * a0.w) + ALPHA_F * xv0.w;
    s1.x = ONE_MINUS_ALPHA * (dv1 * a1.x) + ALPHA_F * xv1.x;
    s1.y = ONE_MINUS_ALPHA * (dv1 * a1.y) + ALPHA_F * xv1.y;
    s1.z = ONE_MINUS_ALPHA * (dv1 * a1.z) + ALPHA_F * xv1.z;
    s1.w = ONE_MINUS_ALPHA * (dv1 * a1.w) + ALPHA_F * xv1.w;

    if (mode) {
        unsigned long long p0 =
            (unsigned long long)f2bf(s0.x)
          | ((unsigned long long)f2bf(s0.y) << 16)
          | ((unsigned long long)f2bf(s0.z) << 32)
          | ((unsigned long long)f2bf(s0.w) << 48);
        __builtin_nontemporal_store(
            p0, (unsigned long long*)(soutb + (size_t)node0 * C + l32 * 4));
        if (ok1) {
            unsigned long long p1 =
                (unsigned long long)f2bf(s1.x)
              | ((unsigned long long)f2bf(s1.y) << 16)
              | ((unsigned long long)f2bf(s1.z) << 32)
              | ((unsigned long long)f2bf(s1.w) << 48);
            __builtin_nontemporal_store(
                p1, (unsigned long long*)(soutb + (size_t)node1 * C + l32 * 4));
        }
    } else {
        ((float4*)soutf)[(size_t)node0 * 32 + l32] = s0;
        if (ok1) ((float4*)soutf)[(size_t)node1 * 32 + l32] = s1;
    }
}

// ---------------- MFMA GEMM (LDS-staged, 64-row tile): out = s @ V + b*beta
// ROUND-12 VERSION (2-tile variant measured +5.5us worse — serialized
// stage/sync chain beats inter-block overlap; keep 1563 independent blocks).
// 16B-granule XOR swizzle (g ^= row&7) -> conflict-free ds_read_b128.
// (LDS staging matters because it converts 16-row-scattered global B-loads
// into ds_read_b128 — NOT an occupancy effect; round-11 no-LDS variant: 50us.)
__global__ __launch_bounds__(256)
void k_out(const float* __restrict__ sinf, const unsigned short* __restrict__ sinb,
           const unsigned short* __restrict__ Vb, const float* __restrict__ bias,
           float* __restrict__ out, int mode, int n) {
    __shared__ unsigned short wlds[128 * 128];  // 32 KB
    __shared__ unsigned short slds[64 * 128];   // 16 KB

    int tid  = threadIdx.x;
    int row0 = blockIdx.x * 64;

    const uint4* Vb16 = (const uint4*)Vb;
    for (int i = tid; i < 2048; i += 256) {
        int j = i >> 4;
        int g = i & 15;
        uint4 v = Vb16[i];
        *(uint4*)&wlds[j * 128 + (g ^ (j & 7)) * 8] = v;
    }

    if (mode) {
        const uint4* sb16 = (const uint4*)sinb;
        for (int i = tid; i < 1024; i += 256) {
            int r = i >> 4;
            int g = i & 15;
            int grow = row0 + r;
            uint4 v = make_uint4(0, 0, 0, 0);
            if (grow < n) v = sb16[(size_t)grow * 16 + g];
            *(uint4*)&slds[r * 128 + (g ^ (r & 7)) * 8] = v;
        }
    } else {
        for (int i = tid; i < 1024; i += 256) {
            int r = i >> 4;
            int g = i & 15;
            int grow = row0 + r;
            union { unsigned short u[8]; uint4 v; } pk;
            if (grow < n) {
                const float* p = sinf + (size_t)grow * C + g * 8;
                float4 aa = *(const float4*)p;
                float4 bb = *(const float4*)(p + 4);
                pk.u[0] = f2bf(aa.x); pk.u[1] = f2bf(aa.y);
                pk.u[2] = f2bf(aa.z); pk.u[3] = f2bf(aa.w);
                pk.u[4] = f2bf(bb.x); pk.u[5] = f2bf(bb.y);
                pk.u[6] = f2bf(bb.z); pk.u[7] = f2bf(bb.w);
            } else {
                pk.v = make_uint4(0, 0, 0, 0);
            }
            *(uint4*)&slds[r * 128 + (g ^ (r & 7)) * 8] = pk.v;
        }
    }
    __syncthreads();

    int w    = tid >> 6;
    int lane = tid & 63;
    int l16  = lane & 15;
    int h    = lane >> 4;
    int arow = w * 16 + l16;

    f32x4 acc[8];
    #pragma unroll
    for (int t = 0; t < 8; ++t) acc[t] = (f32x4){0.f, 0.f, 0.f, 0.f};

    #pragma unroll
    for (int k0 = 0; k0 < 128; k0 += 32) {
        int ga = ((k0 >> 3) + h) ^ (arow & 7);
        bf16x8 a = *(const bf16x8*)&slds[arow * 128 + ga * 8];
        #pragma unroll
        for (int t = 0; t < 8; ++t) {
            int brow = t * 16 + l16;
            int gb = ((k0 >> 3) + h) ^ (brow & 7);
            bf16x8 b = *(const bf16x8*)&wlds[brow * 128 + gb * 8];
            acc[t] = __builtin_amdgcn_mfma_f32_16x16x32_bf16(a, b, acc[t], 0, 0, 0);
        }
    }

    #pragma unroll
    for (int t = 0; t < 8; ++t) {
        int j  = t * 16 + l16;
        float bj = BETA_F * bias[j];
        #pragma unroll
        for (int e2 = 0; e2 < 4; ++e2) {
            int grow = row0 + w * 16 + h * 4 + e2;
            if (grow < n) {
                __builtin_nontemporal_store(acc[t][e2] + bj, &out[(size_t)grow * C + j]);
            }
        }
    }
}

extern "C" void kernel_launch(void* const* d_in, const int* in_sizes, int n_in,
                              void* d_out, int out_size, void* d_ws, size_t ws_size,
                              hipStream_t stream) {
    const float* x   = (const float*)d_in[0];
    const float* x0  = (const float*)d_in[1];
    const float* W   = (const float*)d_in[2];
    const float* b   = (const float*)d_in[3];
    const int*   ei  = (const int*)d_in[4];

    int n = in_sizes[0] / C;
    int e = in_sizes[4] / 2;
    const int* src = ei;
    const int* dst = ei + e;

    int*   cnt        = (int*)d_ws;                    // n
    float* dinv       = (float*)(cnt + n);             // n
    int*   part       = (int*)(dinv + n);              // 512
    int4*  meta       = (int4*)(part + 512);           // n (16B aligned)
    int*   row_ptr    = (int*)(meta + n);              // n
    int*   rank       = row_ptr + n;                   // e
    int*   sorted_src = rank + e;                      // e
    unsigned short* Vb   = (unsigned short*)(sorted_src + e);
    unsigned short* y    = Vb + C * C;                 // n*C
    unsigned short* sb16 = y + (size_t)n * C;          // n*C

    size_t need = (size_t)((char*)(sb16 + (size_t)n * C) - (char*)d_ws);
    int mode = (ws_size >= need) ? 1 : 0;

    float* out = (float*)d_out;

    int nb = (n + 255) / 256;

    {
        void* args[] = {
            (void*)&W, (void*)&Vb, (void*)&cnt, (void*)&rank,
            (void*)&src, (void*)&dst, (void*)&row_ptr, (void*)&meta,
            (void*)&dinv, (void*)&part, (void*)&sorted_src,
            (void*)&x, (void*)&y, (void*)&n, (void*)&e, (void*)&nb
        };
        hipLaunchCooperativeKernel((const void*)k_pre, dim3(1024), dim3(256),
                                   args, 0, stream);
    }
    k_gather<<<(n + 15) / 16, 256, 0, stream>>>(y, x0, sorted_src, meta,
                                                out, sb16, mode, n);
    k_out   <<<(n + 63) / 64, 256, 0, stream>>>(out, sb16, Vb, b, out, mode, n);
}

// Round 18
// 122.897 us; speedup vs baseline: 4.1364x; 4.1364x over previous
//
#include <hip/hip_runtime.h>
#include <stdint.h>

#define C 128
#define ALPHA_F 0.1f
#define ONE_MINUS_ALPHA 0.9f
// beta = log(THETA/LAYER + 1) = log(1.25)
#define BETA_F 0.22314355131420976f
#define ONE_MINUS_BETA 0.7768564486857902f

typedef __attribute__((ext_vector_type(8))) short bf16x8;
typedef __attribute__((ext_vector_type(4))) float f32x4;

__device__ inline float bf2f(unsigned short u) {
    union { unsigned int i; float f; } c;
    c.i = ((unsigned int)u) << 16;
    return c.f;
}
__device__ inline unsigned short f2bf(float f) {
    union { float f; unsigned int i; } c;
    c.f = f;
    unsigned int r = (c.i + 0x7FFFu + ((c.i >> 16) & 1u)) >> 16;  // RNE
    return (unsigned short)r;
}

// ---- init: zero cnt + V = (1-beta)*I + beta*W^T, stored Vb[j][k] bf16 ----
// (kernel zero, NOT hipMemsetAsync: runtime fill kernel measured 40us/400KB.
//  NOT cooperative mega-kernel: grid.sync measured ~100us-class on 8 XCDs.)
__global__ void k_init(const float* __restrict__ W, unsigned short* __restrict__ Vb,
                       int* __restrict__ cnt, int n) {
    int i = blockIdx.x * 256 + threadIdx.x;
    if (i < n) cnt[i] = 0;
    if (i < C * C) {
        int j = i >> 7;   // W row = output index
        int c = i & 127;  // k index
        float v = BETA_F * W[i] + ((j == c) ? ONE_MINUS_BETA : 0.f);
        Vb[i] = f2bf(v);
    }
}

// hist + rank capture: the atomic doubles as the placement rank.
__global__ void k_hist(const int* __restrict__ dst, int* __restrict__ cnt,
                       int* __restrict__ rank, int e) {
    int i = blockIdx.x * blockDim.x + threadIdx.x;
    if (i < e) rank[i] = atomicAdd(&cnt[dst[i]], 1);
}

__global__ __launch_bounds__(256)
void k_scan_a(const int* __restrict__ cnt, int* __restrict__ part, int n) {
    __shared__ int s[256];
    int t = threadIdx.x;
    int i = blockIdx.x * 256 + t;
    s[t] = (i < n) ? cnt[i] : 0;
    __syncthreads();
    for (int off = 128; off > 0; off >>= 1) {
        if (t < off) s[t] += s[t + off];
        __syncthreads();
    }
    if (t == 0) part[blockIdx.x] = s[0];
}

// merged scan_b + scan_c
__global__ __launch_bounds__(256)
void k_scan_bc(const int* __restrict__ cnt, const int* __restrict__ part,
               int4* __restrict__ meta, int* __restrict__ row_ptr,
               float* __restrict__ dinv, int n) {
    __shared__ int a[256];
    __shared__ int b[256];
    int t   = threadIdx.x;
    int bid = blockIdx.x;

    int local = 0;
    for (int k = t; k < bid; k += 256) local += part[k];
    a[t] = local;
    __syncthreads();
    for (int off = 128; off > 0; off >>= 1) {
        if (t < off) a[t] += a[t + off];
        __syncthreads();
    }
    int blockoff = a[0];
    __syncthreads();

    int i = bid * 256 + t;
    int v = (i < n) ? cnt[i] : 0;
    a[t] = v;
    __syncthreads();
    int* cur = a;
    int* nxt = b;
    for (int off = 1; off < 256; off <<= 1) {
        nxt[t] = cur[t] + ((t >= off) ? cur[t - off] : 0);
        __syncthreads();
        int* tmp = cur; cur = nxt; nxt = tmp;
    }
    if (i < n) {
        int rp = blockoff + cur[t] - v;
        float dv = rsqrtf((float)(v + 1));     // deg includes self-loop
        meta[i]    = make_int4(rp, v, __float_as_int(dv), 0);
        row_ptr[i] = rp;
        dinv[i]    = dv;
    }
}

// merged place + ybf: blocks [0,eb) place edges (no atomics); rest build y.
__global__ void k_pl_ybf(const int* __restrict__ src, const int* __restrict__ dst,
                         const int* __restrict__ row_ptr, const int* __restrict__ rank,
                         int* __restrict__ sorted_src, int e,
                         const float* __restrict__ x, const float* __restrict__ dinv,
                         unsigned short* __restrict__ y, int n, int eb) {
    int bid = blockIdx.x;
    if (bid < eb) {
        int i = bid * 256 + threadIdx.x;
        if (i < e) {
            int d = dst[i];
            int pos = row_ptr[d] + rank[i];
            sorted_src[pos] = src[i];
        }
    } else {
        int t = (bid - eb) * 256 + threadIdx.x;
        int total = n * 32;
        if (t < total) {
            int i = t >> 5;
            float dv = dinv[i];
            float4 v = ((const float4*)x)[t];
            ushort4 o;
            o.x = f2bf(v.x * dv);
            o.y = f2bf(v.y * dv);
            o.z = f2bf(v.z * dv);
            o.w = f2bf(v.w * dv);
            ((ushort4*)y)[t] = o;
        }
    }
}

// per-node accumulate: 8 weight-clamped up-front loads + 4-wide batches to 32
// + uniform tail. eidx holds this half-wave's preloaded edge list.
__device__ __forceinline__ float4 acc_node(const ushort4* __restrict__ y4,
                                           const int* __restrict__ ss,
                                           int node, int start, int len,
                                           int eidx, int l32, int base) {
    int m = (len < 32) ? len : 32;
    bool b1 = 1 < m, b2 = 2 < m, b3 = 3 < m;
    bool b4 = 4 < m, b5 = 5 < m, b6 = 6 < m, b7 = 7 < m;
    int s0 = __shfl(eidx, base + 0, 64);
    int s1 = __shfl(eidx, base + (b1 ? 1 : 0), 64);
    int s2 = __shfl(eidx, base + (b2 ? 2 : 0), 64);
    int s3 = __shfl(eidx, base + (b3 ? 3 : 0), 64);
    int s4 = __shfl(eidx, base + (b4 ? 4 : 0), 64);
    int s5 = __shfl(eidx, base + (b5 ? 5 : 0), 64);
    int s6 = __shfl(eidx, base + (b6 ? 6 : 0), 64);
    int s7 = __shfl(eidx, base + (b7 ? 7 : 0), 64);
    ushort4 v0 = y4[(size_t)s0 * 32 + l32];
    ushort4 v1 = y4[(size_t)s1 * 32 + l32];
    ushort4 v2 = y4[(size_t)s2 * 32 + l32];
    ushort4 v3 = y4[(size_t)s3 * 32 + l32];
    ushort4 v4 = y4[(size_t)s4 * 32 + l32];
    ushort4 v5 = y4[(size_t)s5 * 32 + l32];
    ushort4 v6 = y4[(size_t)s6 * 32 + l32];
    ushort4 v7 = y4[(size_t)s7 * 32 + l32];
    ushort4 vs = y4[(size_t)node * 32 + l32];   // self-loop row

    float w0 = (0 < m) ? 1.f : 0.f, w1 = b1 ? 1.f : 0.f, w2 = b2 ? 1.f : 0.f, w3 = b3 ? 1.f : 0.f;
    float w4 = b4 ? 1.f : 0.f, w5 = b5 ? 1.f : 0.f, w6 = b6 ? 1.f : 0.f, w7 = b7 ? 1.f : 0.f;

    float4 acc;
    acc.x = bf2f(vs.x) + w0 * bf2f(v0.x) + w1 * bf2f(v1.x) + w2 * bf2f(v2.x) + w3 * bf2f(v3.x)
                       + w4 * bf2f(v4.x) + w5 * bf2f(v5.x) + w6 * bf2f(v6.x) + w7 * bf2f(v7.x);
    acc.y = bf2f(vs.y) + w0 * bf2f(v0.y) + w1 * bf2f(v1.y) + w2 * bf2f(v2.y) + w3 * bf2f(v3.y)
                       + w4 * bf2f(v4.y) + w5 * bf2f(v5.y) + w6 * bf2f(v6.y) + w7 * bf2f(v7.y);
    acc.z = bf2f(vs.z) + w0 * bf2f(v0.z) + w1 * bf2f(v1.z) + w2 * bf2f(v2.z) + w3 * bf2f(v3.z)
                       + w4 * bf2f(v4.z) + w5 * bf2f(v5.z) + w6 * bf2f(v6.z) + w7 * bf2f(v7.z);
    acc.w = bf2f(vs.w) + w0 * bf2f(v0.w) + w1 * bf2f(v1.w) + w2 * bf2f(v2.w) + w3 * bf2f(v3.w)
                       + w4 * bf2f(v4.w) + w5 * bf2f(v5.w) + w6 * bf2f(v6.w) + w7 * bf2f(v7.w);

    for (int j = 8; j < m; j += 4) {
        bool c1 = (j + 1) < m, c2 = (j + 2) < m, c3 = (j + 3) < m;
        int t0 = __shfl(eidx, base + j, 64);
        int t1 = __shfl(eidx, base + (c1 ? j + 1 : j), 64);
        int t2 = __shfl(eidx, base + (c2 ? j + 2 : j), 64);
        int t3 = __shfl(eidx, base + (c3 ? j + 3 : j), 64);
        ushort4 u0 = y4[(size_t)t0 * 32 + l32];
        ushort4 u1 = y4[(size_t)t1 * 32 + l32];
        ushort4 u2 = y4[(size_t)t2 * 32 + l32];
        ushort4 u3 = y4[(size_t)t3 * 32 + l32];
        float q1 = c1 ? 1.f : 0.f, q2 = c2 ? 1.f : 0.f, q3 = c3 ? 1.f : 0.f;
        acc.x += bf2f(u0.x) + q1 * bf2f(u1.x) + q2 * bf2f(u2.x) + q3 * bf2f(u3.x);
        acc.y += bf2f(u0.y) + q1 * bf2f(u1.y) + q2 * bf2f(u2.y) + q3 * bf2f(u3.y);
        acc.z += bf2f(u0.z) + q1 * bf2f(u1.z) + q2 * bf2f(u2.z) + q3 * bf2f(u3.z);
        acc.w += bf2f(u0.w) + q1 * bf2f(u1.w) + q2 * bf2f(u2.w) + q3 * bf2f(u3.w);
    }

    for (int j = 32; j < len; ++j) {     // rare: degree > 32
        int t0 = ss[start + j];
        ushort4 u0 = y4[(size_t)t0 * 32 + l32];
        acc.x += bf2f(u0.x);
        acc.y += bf2f(u0.y);
        acc.z += bf2f(u0.z);
        acc.w += bf2f(u0.w);
    }
    return acc;
}

// ---------------- gather + alpha-blend -> s (bf16 ws or fp32 d_out) --------
// 2 nodes per HALF-WAVE, front-loads paired (kernel-level 42.8 -> 40.0us).
__global__ __launch_bounds__(256)
void k_gather(const unsigned short* __restrict__ y, const float* __restrict__ x0,
              const int* __restrict__ sorted_src, const int4* __restrict__ meta,
              float* __restrict__ soutf, unsigned short* __restrict__ soutb,
              int mode, int n) {
    int tid  = threadIdx.x;
    int l32  = tid & 31;
    int base = tid & 32;
    int hw   = tid >> 5;                  // 0..7 half-wave in block
    int node0 = blockIdx.x * 16 + hw * 2;
    if (node0 >= n) return;
    int node1 = node0 + 1;
    bool ok1 = node1 < n;
    int vn1 = ok1 ? node1 : node0;

    const ushort4* y4 = (const ushort4*)y;
    const f32x4* x04 = (const f32x4*)x0;

    int4 md0 = meta[node0];
    int4 md1 = meta[vn1];
    int m0 = (md0.y < 32) ? md0.y : 32;
    int m1 = (md1.y < 32) ? md1.y : 32;
    int e0 = (l32 < m0) ? sorted_src[md0.x + l32] : node0;
    int e1 = (l32 < m1) ? sorted_src[md1.x + l32] : vn1;
    f32x4 xv0 = __builtin_nontemporal_load(x04 + (size_t)node0 * 32 + l32);
    f32x4 xv1 = __builtin_nontemporal_load(x04 + (size_t)vn1 * 32 + l32);

    float4 a0 = acc_node(y4, sorted_src, node0, md0.x, md0.y, e0, l32, base);
    float4 a1 = acc_node(y4, sorted_src, vn1,   md1.x, md1.y, e1, l32, base);

    float dv0 = __int_as_float(md0.z);
    float dv1 = __int_as_float(md1.z);

    float4 s0, s1;
    s0.x = ONE_MINUS_ALPHA * (dv0 * a0.x) + ALPHA_F * xv0.x;
    s0.y = ONE_MINUS_ALPHA * (dv0 * a0.y) + ALPHA_F * xv0.y;
    s0.z = ONE_MINUS_ALPHA * (dv0 * a0.z) + ALPHA_F * xv0.z;
    s0.w = ONE_MINUS_ALPHA * (dv0 * a0.w) + ALPHA_F * xv0.w;
    s1.x = ONE_MINUS_ALPHA * (dv1 * a1.x) + ALPHA_F * xv1.x;
    s1.y = ONE_MINUS_ALPHA * (dv1 * a1.y) + ALPHA_F * xv1.y;
    s1.z = ONE_MINUS_ALPHA * (dv1 * a1.z) + ALPHA_F * xv1.z;
    s1.w = ONE_MINUS_ALPHA * (dv1 * a1.w) + ALPHA_F * xv1.w;

    if (mode) {
        unsigned long long p0 =
            (unsigned long long)f2bf(s0.x)
          | ((unsigned long long)f2bf(s0.y) << 16)
          | ((unsigned long long)f2bf(s0.z) << 32)
          | ((unsigned long long)f2bf(s0.w) << 48);
        __builtin_nontemporal_store(
            p0, (unsigned long long*)(soutb + (size_t)node0 * C + l32 * 4));
        if (ok1) {
            unsigned long long p1 =
                (unsigned long long)f2bf(s1.x)
              | ((unsigned long long)f2bf(s1.y) << 16)
              | ((unsigned long long)f2bf(s1.z) << 32)
              | ((unsigned long long)f2bf(s1.w) << 48);
            __builtin_nontemporal_store(
                p1, (unsigned long long*)(soutb + (size_t)node1 * C + l32 * 4));
        }
    } else {
        ((float4*)soutf)[(size_t)node0 * 32 + l32] = s0;
        if (ok1) ((float4*)soutf)[(size_t)node1 * 32 + l32] = s1;
    }
}

// ---------------- MFMA GEMM: out = s @ V + beta*b ----------------
// B (Vb) LDS-staged — round 11 proved B MUST be LDS (32 scattered loads/wave
// from global = 50us kernel). A-fragments straight from global: only 4
// loads/wave/k-step against L3-resident sb16; drops slds (48->32KB LDS,
// 5 blocks/CU), the 1024-iter staging loop, and one barrier.
__global__ __launch_bounds__(256)
void k_out(const float* __restrict__ sinf, const unsigned short* __restrict__ sinb,
           const unsigned short* __restrict__ Vb, const float* __restrict__ bias,
           float* __restrict__ out, int mode, int n) {
    __shared__ unsigned short wlds[128 * 128];  // 32 KB

    int tid  = threadIdx.x;
    int row0 = blockIdx.x * 64;

    const uint4* Vb16 = (const uint4*)Vb;
    for (int i = tid; i < 2048; i += 256) {
        int j = i >> 4;
        int g = i & 15;
        uint4 v = Vb16[i];
        *(uint4*)&wlds[j * 128 + (g ^ (j & 7)) * 8] = v;
    }
    __syncthreads();

    int w    = tid >> 6;
    int lane = tid & 63;
    int l16  = lane & 15;
    int h    = lane >> 4;
    int arow = row0 + w * 16 + l16;
    int arow_c = (arow < n) ? arow : (n - 1);   // clamped: garbage rows feed
                                                // only unguarded-unstored D-rows

    f32x4 acc[8];
    #pragma unroll
    for (int t = 0; t < 8; ++t) acc[t] = (f32x4){0.f, 0.f, 0.f, 0.f};

    #pragma unroll
    for (int k0 = 0; k0 < 128; k0 += 32) {
        bf16x8 a;
        if (mode) {
            a = *(const bf16x8*)(sinb + (size_t)arow_c * C + k0 + h * 8);
        } else {
            const float* ap = sinf + (size_t)arow_c * C + k0 + h * 8;
            float4 aa = *(const float4*)ap;
            float4 ab = *(const float4*)(ap + 4);
            union { unsigned short u[8]; bf16x8 v; } pk;
            pk.u[0] = f2bf(aa.x); pk.u[1] = f2bf(aa.y);
            pk.u[2] = f2bf(aa.z); pk.u[3] = f2bf(aa.w);
            pk.u[4] = f2bf(ab.x); pk.u[5] = f2bf(ab.y);
            pk.u[6] = f2bf(ab.z); pk.u[7] = f2bf(ab.w);
            a = pk.v;
        }
        #pragma unroll
        for (int t = 0; t < 8; ++t) {
            int brow = t * 16 + l16;
            int gb = ((k0 >> 3) + h) ^ (brow & 7);
            bf16x8 b = *(const bf16x8*)&wlds[brow * 128 + gb * 8];
            acc[t] = __builtin_amdgcn_mfma_f32_16x16x32_bf16(a, b, acc[t], 0, 0, 0);
        }
    }

    #pragma unroll
    for (int t = 0; t < 8; ++t) {
        int j  = t * 16 + l16;
        float bj = BETA_F * bias[j];
        #pragma unroll
        for (int e2 = 0; e2 < 4; ++e2) {
            int grow = row0 + w * 16 + h * 4 + e2;
            if (grow < n) {
                __builtin_nontemporal_store(acc[t][e2] + bj, &out[(size_t)grow * C + j]);
            }
        }
    }
}

extern "C" void kernel_launch(void* const* d_in, const int* in_sizes, int n_in,
                              void* d_out, int out_size, void* d_ws, size_t ws_size,
                              hipStream_t stream) {
    const float* x   = (const float*)d_in[0];
    const float* x0  = (const float*)d_in[1];
    const float* W   = (const float*)d_in[2];
    const float* b   = (const float*)d_in[3];
    const int*   ei  = (const int*)d_in[4];

    int n = in_sizes[0] / C;
    int e = in_sizes[4] / 2;
    const int* src = ei;
    const int* dst = ei + e;

    int*   cnt        = (int*)d_ws;                    // n
    float* dinv       = (float*)(cnt + n);             // n
    int*   part       = (int*)(dinv + n);              // 512
    int4*  meta       = (int4*)(part + 512);           // n (16B aligned)
    int*   row_ptr    = (int*)(meta + n);              // n
    int*   rank       = row_ptr + n;                   // e
    int*   sorted_src = rank + e;                      // e
    unsigned short* Vb   = (unsigned short*)(sorted_src + e);
    unsigned short* y    = Vb + C * C;                 // n*C
    unsigned short* sb16 = y + (size_t)n * C;          // n*C

    size_t need = (size_t)((char*)(sb16 + (size_t)n * C) - (char*)d_ws);
    int mode = (ws_size >= need) ? 1 : 0;

    float* out = (float*)d_out;

    int nb  = (n + 255) / 256;
    int eb  = (e + 255) / 256;
    int ybg = (n * 32 + 255) / 256;

    k_init   <<<nb, 256, 0, stream>>>(W, Vb, cnt, n);
    k_hist   <<<eb, 256, 0, stream>>>(dst, cnt, rank, e);
    k_scan_a <<<nb, 256, 0, stream>>>(cnt, part, n);
    k_scan_bc<<<nb, 256, 0, stream>>>(cnt, part, meta, row_ptr, dinv, n);
    k_pl_ybf <<<eb + ybg, 256, 0, stream>>>(src, dst, row_ptr, rank, sorted_src, e,
                                            x, dinv, y, n, eb);
    k_gather <<<(n + 15) / 16, 256, 0, stream>>>(y, x0, sorted_src, meta,
                                                 out, sb16, mode, n);
    k_out    <<<(n + 63) / 64, 256, 0, stream>>>(out, sb16, Vb, b, out, mode, n);
}

// Round 19
// 121.641 us; speedup vs baseline: 4.1791x; 1.0103x over previous
//
#include <hip/hip_runtime.h>
#include <stdint.h>

#define C 128
#define ALPHA_F 0.1f
#define ONE_MINUS_ALPHA 0.9f
// beta = log(THETA/LAYER + 1) = log(1.25)
#define BETA_F 0.22314355131420976f
#define ONE_MINUS_BETA 0.7768564486857902f
#define KSLOT 32

typedef __attribute__((ext_vector_type(8))) short bf16x8;
typedef __attribute__((ext_vector_type(4))) float f32x4;

__device__ inline float bf2f(unsigned short u) {
    union { unsigned int i; float f; } c;
    c.i = ((unsigned int)u) << 16;
    return c.f;
}
__device__ inline unsigned short f2bf(float f) {
    union { float f; unsigned int i; } c;
    c.f = f;
    unsigned int r = (c.i + 0x7FFFu + ((c.i >> 16) & 1u)) >> 16;  // RNE
    return (unsigned short)r;
}

// ---- init: zero cnt + ovf counter + V = (1-beta)*I + beta*W^T (bf16) ----
// (kernel zero, NOT hipMemsetAsync: runtime fill kernel measured 40us/400KB.
//  NOT cooperative mega-kernel: grid.sync measured ~100us-class on 8 XCDs.)
__global__ void k_init(const float* __restrict__ W, unsigned short* __restrict__ Vb,
                       int* __restrict__ cnt, int* __restrict__ ovf_cnt, int n) {
    int i = blockIdx.x * 256 + threadIdx.x;
    if (i == 0) *ovf_cnt = 0;
    if (i < n) cnt[i] = 0;
    if (i < C * C) {
        int j = i >> 7;   // W row = output index
        int c = i & 127;  // k index
        float v = BETA_F * W[i] + ((j == c) ? ONE_MINUS_BETA : 0.f);
        Vb[i] = f2bf(v);
    }
}

// hist + DIRECT placement into fixed-stride CSR (row_ptr == d*KSLOT; the
// atomic's return value is the slot index). Kills scan_a/scan_bc/place/rank.
// Overflow (deg > KSLOT, ~never for Poisson(6.4)) -> atomic-append list.
__global__ void k_hist_place(const int* __restrict__ src, const int* __restrict__ dst,
                             int* __restrict__ cnt, int* __restrict__ sorted_src,
                             int* __restrict__ ovf_src, int* __restrict__ ovf_dst,
                             int* __restrict__ ovf_cnt, int e) {
    int i = blockIdx.x * blockDim.x + threadIdx.x;
    if (i < e) {
        int d = dst[i];
        int r = atomicAdd(&cnt[d], 1);
        if (r < KSLOT) {
            sorted_src[(size_t)d * KSLOT + r] = src[i];
        } else {
            int p = atomicAdd(ovf_cnt, 1);
            ovf_src[p] = src[i];
            ovf_dst[p] = d;
        }
    }
}

// y[i][:] = bf16(x[i][:] * rsqrt(deg_i+1)); dinv recomputed from cnt (no array)
__global__ void k_ybf(const float* __restrict__ x, const int* __restrict__ cnt,
                      unsigned short* __restrict__ y, int n) {
    int t = blockIdx.x * 256 + threadIdx.x;
    int total = n * 32;
    if (t < total) {
        int i = t >> 5;
        float dv = rsqrtf((float)(cnt[i] + 1));
        float4 v = ((const float4*)x)[t];
        ushort4 o;
        o.x = f2bf(v.x * dv);
        o.y = f2bf(v.y * dv);
        o.z = f2bf(v.z * dv);
        o.w = f2bf(v.w * dv);
        ((ushort4*)y)[t] = o;
    }
}

// per-node accumulate: 8 weight-clamped up-front loads + 4-wide batches to
// KSLOT. eidx = this half-wave's preloaded edge list (coalesced 128B read).
__device__ __forceinline__ float4 acc_node(const ushort4* __restrict__ y4,
                                           int node, int len,
                                           int eidx, int l32, int base) {
    int m = (len < KSLOT) ? len : KSLOT;
    bool b1 = 1 < m, b2 = 2 < m, b3 = 3 < m;
    bool b4 = 4 < m, b5 = 5 < m, b6 = 6 < m, b7 = 7 < m;
    int s0 = __shfl(eidx, base + 0, 64);
    int s1 = __shfl(eidx, base + (b1 ? 1 : 0), 64);
    int s2 = __shfl(eidx, base + (b2 ? 2 : 0), 64);
    int s3 = __shfl(eidx, base + (b3 ? 3 : 0), 64);
    int s4 = __shfl(eidx, base + (b4 ? 4 : 0), 64);
    int s5 = __shfl(eidx, base + (b5 ? 5 : 0), 64);
    int s6 = __shfl(eidx, base + (b6 ? 6 : 0), 64);
    int s7 = __shfl(eidx, base + (b7 ? 7 : 0), 64);
    ushort4 v0 = y4[(size_t)s0 * 32 + l32];
    ushort4 v1 = y4[(size_t)s1 * 32 + l32];
    ushort4 v2 = y4[(size_t)s2 * 32 + l32];
    ushort4 v3 = y4[(size_t)s3 * 32 + l32];
    ushort4 v4 = y4[(size_t)s4 * 32 + l32];
    ushort4 v5 = y4[(size_t)s5 * 32 + l32];
    ushort4 v6 = y4[(size_t)s6 * 32 + l32];
    ushort4 v7 = y4[(size_t)s7 * 32 + l32];
    ushort4 vs = y4[(size_t)node * 32 + l32];   // self-loop row

    float w0 = (0 < m) ? 1.f : 0.f, w1 = b1 ? 1.f : 0.f, w2 = b2 ? 1.f : 0.f, w3 = b3 ? 1.f : 0.f;
    float w4 = b4 ? 1.f : 0.f, w5 = b5 ? 1.f : 0.f, w6 = b6 ? 1.f : 0.f, w7 = b7 ? 1.f : 0.f;

    float4 acc;
    acc.x = bf2f(vs.x) + w0 * bf2f(v0.x) + w1 * bf2f(v1.x) + w2 * bf2f(v2.x) + w3 * bf2f(v3.x)
                       + w4 * bf2f(v4.x) + w5 * bf2f(v5.x) + w6 * bf2f(v6.x) + w7 * bf2f(v7.x);
    acc.y = bf2f(vs.y) + w0 * bf2f(v0.y) + w1 * bf2f(v1.y) + w2 * bf2f(v2.y) + w3 * bf2f(v3.y)
                       + w4 * bf2f(v4.y) + w5 * bf2f(v5.y) + w6 * bf2f(v6.y) + w7 * bf2f(v7.y);
    acc.z = bf2f(vs.z) + w0 * bf2f(v0.z) + w1 * bf2f(v1.z) + w2 * bf2f(v2.z) + w3 * bf2f(v3.z)
                       + w4 * bf2f(v4.z) + w5 * bf2f(v5.z) + w6 * bf2f(v6.z) + w7 * bf2f(v7.z);
    acc.w = bf2f(vs.w) + w0 * bf2f(v0.w) + w1 * bf2f(v1.w) + w2 * bf2f(v2.w) + w3 * bf2f(v3.w)
                       + w4 * bf2f(v4.w) + w5 * bf2f(v5.w) + w6 * bf2f(v6.w) + w7 * bf2f(v7.w);

    for (int j = 8; j < m; j += 4) {
        bool c1 = (j + 1) < m, c2 = (j + 2) < m, c3 = (j + 3) < m;
        int t0 = __shfl(eidx, base + j, 64);
        int t1 = __shfl(eidx, base + (c1 ? j + 1 : j), 64);
        int t2 = __shfl(eidx, base + (c2 ? j + 2 : j), 64);
        int t3 = __shfl(eidx, base + (c3 ? j + 3 : j), 64);
        ushort4 u0 = y4[(size_t)t0 * 32 + l32];
        ushort4 u1 = y4[(size_t)t1 * 32 + l32];
        ushort4 u2 = y4[(size_t)t2 * 32 + l32];
        ushort4 u3 = y4[(size_t)t3 * 32 + l32];
        float q1 = c1 ? 1.f : 0.f, q2 = c2 ? 1.f : 0.f, q3 = c3 ? 1.f : 0.f;
        acc.x += bf2f(u0.x) + q1 * bf2f(u1.x) + q2 * bf2f(u2.x) + q3 * bf2f(u3.x);
        acc.y += bf2f(u0.y) + q1 * bf2f(u1.y) + q2 * bf2f(u2.y) + q3 * bf2f(u3.y);
        acc.z += bf2f(u0.z) + q1 * bf2f(u1.z) + q2 * bf2f(u2.z) + q3 * bf2f(u3.z);
        acc.w += bf2f(u0.w) + q1 * bf2f(u1.w) + q2 * bf2f(u2.w) + q3 * bf2f(u3.w);
    }
    return acc;
}

// overflow edges for this node (deg > KSLOT): scan the (almost always empty)
// overflow list, filter by dst == node. Correct for any degree distribution.
__device__ __forceinline__ float4 add_ovf(float4 acc, const ushort4* __restrict__ y4,
                                          const int* __restrict__ ovf_src,
                                          const int* __restrict__ ovf_dst,
                                          int oc, int node, int l32) {
    for (int j = 0; j < oc; ++j) {
        if (ovf_dst[j] == node) {
            ushort4 u = y4[(size_t)ovf_src[j] * 32 + l32];
            acc.x += bf2f(u.x);
            acc.y += bf2f(u.y);
            acc.z += bf2f(u.z);
            acc.w += bf2f(u.w);
        }
    }
    return acc;
}

// ---------------- gather + alpha-blend -> s (bf16 ws or fp32 d_out) --------
// 2 nodes per HALF-WAVE, front-loads paired (kernel-level 42.8 -> 40.0us).
// Fixed-stride CSR: edge-list read is coalesced 128B at node*128.
__global__ __launch_bounds__(256)
void k_gather(const unsigned short* __restrict__ y, const float* __restrict__ x0,
              const int* __restrict__ sorted_src, const int* __restrict__ cnt,
              const int* __restrict__ ovf_src, const int* __restrict__ ovf_dst,
              const int* __restrict__ ovf_cnt,
              float* __restrict__ soutf, unsigned short* __restrict__ soutb,
              int mode, int n) {
    int tid  = threadIdx.x;
    int l32  = tid & 31;
    int base = tid & 32;
    int hw   = tid >> 5;                  // 0..7 half-wave in block
    int node0 = blockIdx.x * 16 + hw * 2;
    if (node0 >= n) return;
    int node1 = node0 + 1;
    bool ok1 = node1 < n;
    int vn1 = ok1 ? node1 : node0;

    const ushort4* y4 = (const ushort4*)y;
    const f32x4* x04 = (const f32x4*)x0;

    // paired front-loads (all independent)
    int len0 = cnt[node0];
    int len1 = cnt[vn1];
    int m0 = (len0 < KSLOT) ? len0 : KSLOT;
    int m1 = (len1 < KSLOT) ? len1 : KSLOT;
    int e0 = (l32 < m0) ? sorted_src[(size_t)node0 * KSLOT + l32] : node0;
    int e1 = (l32 < m1) ? sorted_src[(size_t)vn1 * KSLOT + l32] : vn1;
    f32x4 xv0 = __builtin_nontemporal_load(x04 + (size_t)node0 * 32 + l32);
    f32x4 xv1 = __builtin_nontemporal_load(x04 + (size_t)vn1 * 32 + l32);

    float4 a0 = acc_node(y4, node0, len0, e0, l32, base);
    float4 a1 = acc_node(y4, vn1,   len1, e1, l32, base);

    if (len0 > KSLOT || len1 > KSLOT) {   // ~never; correct for any input
        int oc = *ovf_cnt;
        if (len0 > KSLOT) a0 = add_ovf(a0, y4, ovf_src, ovf_dst, oc, node0, l32);
        if (len1 > KSLOT) a1 = add_ovf(a1, y4, ovf_src, ovf_dst, oc, vn1, l32);
    }

    float dv0 = rsqrtf((float)(len0 + 1));
    float dv1 = rsqrtf((float)(len1 + 1));

    float4 s0, s1;
    s0.x = ONE_MINUS_ALPHA * (dv0 * a0.x) + ALPHA_F * xv0.x;
    s0.y = ONE_MINUS_ALPHA * (dv0 * a0.y) + ALPHA_F * xv0.y;
    s0.z = ONE_MINUS_ALPHA * (dv0 * a0.z) + ALPHA_F * xv0.z;
    s0.w = ONE_MINUS_ALPHA * (dv0 * a0.w) + ALPHA_F * xv0.w;
    s1.x = ONE_MINUS_ALPHA * (dv1 * a1.x) + ALPHA_F * xv1.x;
    s1.y = ONE_MINUS_ALPHA * (dv1 * a1.y) + ALPHA_F * xv1.y;
    s1.z = ONE_MINUS_ALPHA * (dv1 * a1.z) + ALPHA_F * xv1.z;
    s1.w = ONE_MINUS_ALPHA * (dv1 * a1.w) + ALPHA_F * xv1.w;

    if (mode) {
        unsigned long long p0 =
            (unsigned long long)f2bf(s0.x)
          | ((unsigned long long)f2bf(s0.y) << 16)
          | ((unsigned long long)f2bf(s0.z) << 32)
          | ((unsigned long long)f2bf(s0.w) << 48);
        __builtin_nontemporal_store(
            p0, (unsigned long long*)(soutb + (size_t)node0 * C + l32 * 4));
        if (ok1) {
            unsigned long long p1 =
                (unsigned long long)f2bf(s1.x)
              | ((unsigned long long)f2bf(s1.y) << 16)
              | ((unsigned long long)f2bf(s1.z) << 32)
              | ((unsigned long long)f2bf(s1.w) << 48);
            __builtin_nontemporal_store(
                p1, (unsigned long long*)(soutb + (size_t)node1 * C + l32 * 4));
        }
    } else {
        ((float4*)soutf)[(size_t)node0 * 32 + l32] = s0;
        if (ok1) ((float4*)soutf)[(size_t)node1 * 32 + l32] = s1;
    }
}

// ---------------- MFMA GEMM: out = s @ V + beta*b ----------------
// B (Vb) LDS-staged — round 11 proved B MUST be LDS (32 scattered loads/wave
// from global = 50us kernel). A-fragments straight from global (round 18:
// 126.3 -> 122.9us): only 4 loads/wave/k-step against L3-resident sb16.
__global__ __launch_bounds__(256)
void k_out(const float* __restrict__ sinf, const unsigned short* __restrict__ sinb,
           const unsigned short* __restrict__ Vb, const float* __restrict__ bias,
           float* __restrict__ out, int mode, int n) {
    __shared__ unsigned short wlds[128 * 128];  // 32 KB

    int tid  = threadIdx.x;
    int row0 = blockIdx.x * 64;

    const uint4* Vb16 = (const uint4*)Vb;
    for (int i = tid; i < 2048; i += 256) {
        int j = i >> 4;
        int g = i & 15;
        uint4 v = Vb16[i];
        *(uint4*)&wlds[j * 128 + (g ^ (j & 7)) * 8] = v;
    }
    __syncthreads();

    int w    = tid >> 6;
    int lane = tid & 63;
    int l16  = lane & 15;
    int h    = lane >> 4;
    int arow = row0 + w * 16 + l16;
    int arow_c = (arow < n) ? arow : (n - 1);   // clamped: garbage rows feed
                                                // only unguarded-unstored D-rows

    f32x4 acc[8];
    #pragma unroll
    for (int t = 0; t < 8; ++t) acc[t] = (f32x4){0.f, 0.f, 0.f, 0.f};

    #pragma unroll
    for (int k0 = 0; k0 < 128; k0 += 32) {
        bf16x8 a;
        if (mode) {
            a = *(const bf16x8*)(sinb + (size_t)arow_c * C + k0 + h * 8);
        } else {
            const float* ap = sinf + (size_t)arow_c * C + k0 + h * 8;
            float4 aa = *(const float4*)ap;
            float4 ab = *(const float4*)(ap + 4);
            union { unsigned short u[8]; bf16x8 v; } pk;
            pk.u[0] = f2bf(aa.x); pk.u[1] = f2bf(aa.y);
            pk.u[2] = f2bf(aa.z); pk.u[3] = f2bf(aa.w);
            pk.u[4] = f2bf(ab.x); pk.u[5] = f2bf(ab.y);
            pk.u[6] = f2bf(ab.z); pk.u[7] = f2bf(ab.w);
            a = pk.v;
        }
        #pragma unroll
        for (int t = 0; t < 8; ++t) {
            int brow = t * 16 + l16;
            int gb = ((k0 >> 3) + h) ^ (brow & 7);
            bf16x8 b = *(const bf16x8*)&wlds[brow * 128 + gb * 8];
            acc[t] = __builtin_amdgcn_mfma_f32_16x16x32_bf16(a, b, acc[t], 0, 0, 0);
        }
    }

    #pragma unroll
    for (int t = 0; t < 8; ++t) {
        int j  = t * 16 + l16;
        float bj = BETA_F * bias[j];
        #pragma unroll
        for (int e2 = 0; e2 < 4; ++e2) {
            int grow = row0 + w * 16 + h * 4 + e2;
            if (grow < n) {
                __builtin_nontemporal_store(acc[t][e2] + bj, &out[(size_t)grow * C + j]);
            }
        }
    }
}

extern "C" void kernel_launch(void* const* d_in, const int* in_sizes, int n_in,
                              void* d_out, int out_size, void* d_ws, size_t ws_size,
                              hipStream_t stream) {
    const float* x   = (const float*)d_in[0];
    const float* x0  = (const float*)d_in[1];
    const float* W   = (const float*)d_in[2];
    const float* b   = (const float*)d_in[3];
    const int*   ei  = (const int*)d_in[4];

    int n = in_sizes[0] / C;
    int e = in_sizes[4] / 2;
    const int* src = ei;
    const int* dst = ei + e;

    int*   cnt        = (int*)d_ws;                      // n
    int*   sorted_src = cnt + n;                         // n*KSLOT (12.8 MB)
    int*   ovf_src    = sorted_src + (size_t)n * KSLOT;  // e
    int*   ovf_dst    = ovf_src + e;                     // e
    int*   ovf_cnt    = ovf_dst + e;                     // 16 (pad)
    unsigned short* Vb   = (unsigned short*)(ovf_cnt + 16);
    unsigned short* y    = Vb + C * C;                   // n*C
    unsigned short* sb16 = y + (size_t)n * C;            // n*C

    size_t need = (size_t)((char*)(sb16 + (size_t)n * C) - (char*)d_ws);
    int mode = (ws_size >= need) ? 1 : 0;

    float* out = (float*)d_out;

    int nb  = (n + 255) / 256;
    int eb  = (e + 255) / 256;
    int ybg = (n * 32 + 255) / 256;

    k_init      <<<nb, 256, 0, stream>>>(W, Vb, cnt, ovf_cnt, n);
    k_hist_place<<<eb, 256, 0, stream>>>(src, dst, cnt, sorted_src,
                                         ovf_src, ovf_dst, ovf_cnt, e);
    k_ybf       <<<ybg, 256, 0, stream>>>(x, cnt, y, n);
    k_gather    <<<(n + 15) / 16, 256, 0, stream>>>(y, x0, sorted_src, cnt,
                                                    ovf_src, ovf_dst, ovf_cnt,
                                                    out, sb16, mode, n);
    k_out       <<<(n + 63) / 64, 256, 0, stream>>>(out, sb16, Vb, b, out, mode, n);
}